// Round 2
// baseline (233.601 us; speedup 1.0000x reference)
//
#include <hip/hip_runtime.h>
#include <hip/hip_bf16.h>

// MessagePassing: out[t] += x[s] for each edge (t, s), D=64.
// edge_index: [2, E] int32 (row 0 = targets, row 1 = sources), x: [N, 64] f32.
//
// Strategy: counting-sort edges by target into a CSR (ws scratch), then
// segment-sum with one wave per node -> zero fp32 atomics, out written once.

#define D 64
#define SCAN_THREADS 1024

__global__ void hist_kernel(const int* __restrict__ tgt, int* __restrict__ cnt, int E) {
    int e = blockIdx.x * blockDim.x + threadIdx.x;
    if (e < E) atomicAdd(&cnt[tgt[e]], 1);
}

// Single-block exclusive scan over cnt[0..N) -> off[0..N] and run[0..N) (copy of off).
__global__ __launch_bounds__(SCAN_THREADS) void scan_kernel(const int* __restrict__ cnt,
                                                            int* __restrict__ off,
                                                            int* __restrict__ run, int N) {
    __shared__ int sums[SCAN_THREADS];
    int tid = threadIdx.x;
    int chunk = (N + SCAN_THREADS - 1) / SCAN_THREADS;
    int lo = tid * chunk;
    int hi = lo + chunk; if (hi > N) hi = N;
    int s = 0;
    for (int i = lo; i < hi; ++i) s += cnt[i];
    sums[tid] = s;
    __syncthreads();
    // Hillis-Steele inclusive scan
    for (int d = 1; d < SCAN_THREADS; d <<= 1) {
        int v = (tid >= d) ? sums[tid - d] : 0;
        __syncthreads();
        sums[tid] += v;
        __syncthreads();
    }
    int p = (tid == 0) ? 0 : sums[tid - 1];  // exclusive prefix of this chunk
    for (int i = lo; i < hi; ++i) {
        int c = cnt[i];
        off[i] = p;
        run[i] = p;
        p += c;
    }
    if (tid == SCAN_THREADS - 1) off[N] = sums[SCAN_THREADS - 1];
}

__global__ void scatter_kernel(const int* __restrict__ tgt, const int* __restrict__ src,
                               int* __restrict__ run, int* __restrict__ ssrc, int E) {
    int e = blockIdx.x * blockDim.x + threadIdx.x;
    if (e < E) {
        int pos = atomicAdd(&run[tgt[e]], 1);
        ssrc[pos] = src[e];
    }
}

// One wave (64 lanes) per node; lane = feature dim. Gathers are 256B coalesced.
__global__ __launch_bounds__(256) void segsum_kernel(const int* __restrict__ off,
                                                     const int* __restrict__ ssrc,
                                                     const float* __restrict__ x,
                                                     float* __restrict__ out, int N) {
    int wave = (int)((blockIdx.x * (unsigned)blockDim.x + threadIdx.x) >> 6);
    int lane = threadIdx.x & 63;
    if (wave >= N) return;
    int start = off[wave];
    int end = off[wave + 1];
    float acc = 0.f;
    for (int i = start; i < end; i += 64) {
        int n = end - i; if (n > 64) n = 64;
        // coalesced load of up to 64 upcoming source ids, broadcast via shfl
        int idx = (i + lane < end) ? ssrc[i + lane] : 0;
        int j = 0;
        for (; j + 3 < n; j += 4) {
            int s0 = __shfl(idx, j);
            int s1 = __shfl(idx, j + 1);
            int s2 = __shfl(idx, j + 2);
            int s3 = __shfl(idx, j + 3);
            float v0 = x[(long long)s0 * D + lane];
            float v1 = x[(long long)s1 * D + lane];
            float v2 = x[(long long)s2 * D + lane];
            float v3 = x[(long long)s3 * D + lane];
            acc += v0; acc += v1; acc += v2; acc += v3;
        }
        for (; j < n; ++j) {
            int s0 = __shfl(idx, j);
            acc += x[(long long)s0 * D + lane];
        }
    }
    out[(long long)wave * D + lane] = acc;
}

// Fallback (ws too small): direct atomic scatter-add, as in round 1.
__global__ void mp_scatter_add_kernel(const int* __restrict__ tgt,
                                      const int* __restrict__ src,
                                      const float* __restrict__ x,
                                      float* __restrict__ out,
                                      int E) {
    long long tid = (long long)blockIdx.x * blockDim.x + threadIdx.x;
    int e = (int)(tid >> 6);
    int d = (int)(tid & 63);
    if (e >= E) return;
    atomicAdd(&out[(long long)tgt[e] * D + d], x[(long long)src[e] * D + d]);
}

extern "C" void kernel_launch(void* const* d_in, const int* in_sizes, int n_in,
                              void* d_out, int out_size, void* d_ws, size_t ws_size,
                              hipStream_t stream) {
    const int* edge_index = (const int*)d_in[0];   // [2, E]
    const float* x        = (const float*)d_in[1]; // [N, 64]
    float* out            = (float*)d_out;         // [N, 64]

    int E = in_sizes[0] / 2;
    int N = out_size / D;
    const int* tgt = edge_index;       // edge_index[0]
    const int* src = edge_index + E;   // edge_index[1]

    // ws layout: off[N+1] | run[N] | cnt[N] | ssrc[E]   (all int32)
    size_t need = ((size_t)(N + 1) + N + N + E) * sizeof(int);
    if (ws_size < need) {
        // fallback: atomic scatter-add
        hipMemsetAsync(d_out, 0, (size_t)out_size * sizeof(float), stream);
        long long total = (long long)E * D;
        int block = 256;
        long long grid = (total + block - 1) / block;
        mp_scatter_add_kernel<<<(dim3)(unsigned)grid, block, 0, stream>>>(tgt, src, x, out, E);
        return;
    }

    int* off  = (int*)d_ws;
    int* run  = off + (N + 1);
    int* cnt  = run + N;
    int* ssrc = cnt + N;

    hipMemsetAsync(cnt, 0, (size_t)N * sizeof(int), stream);

    int block = 256;
    int gridE = (E + block - 1) / block;
    hist_kernel<<<gridE, block, 0, stream>>>(tgt, cnt, E);
    scan_kernel<<<1, SCAN_THREADS, 0, stream>>>(cnt, off, run, N);
    scatter_kernel<<<gridE, block, 0, stream>>>(tgt, src, run, ssrc, E);

    long long total = (long long)N * D;
    long long gridN = (total + block - 1) / block;
    segsum_kernel<<<(dim3)(unsigned)gridN, block, 0, stream>>>(off, ssrc, x, out, N);
}

// Round 4
// 130.248 us; speedup vs baseline: 1.7935x; 1.7935x over previous
//
#include <hip/hip_runtime.h>
#include <hip/hip_bf16.h>

// MessagePassing: out[t] += x[s] for each edge (t, s), D=64.
// edge_index: [2, E] int32 (row 0 = targets, row 1 = sources), x: [N, 64] f32.
//
// CSR counting-sort by target, then atomic-free segment-sum (one wave/node).
// Round-4 fix: segsum inner loop made wave-uniform — round 3's per-group loop
// bounds diverged, and __shfl (ds_bpermute) from an exited (inactive) lane is
// undefined on CDNA. Now trips = ceil(n/4) for ALL groups; shfl runs with all
// 64 lanes active; only the load/accumulate is predicated.

#define D 64
#define SCAN_B 256
#define SCAN_E 1024   // elements per scan block (4 per thread)

__global__ void hist_kernel(const int* __restrict__ tgt, int* __restrict__ cnt, int E) {
    int e = blockIdx.x * blockDim.x + threadIdx.x;
    if (e < E) atomicAdd(&cnt[tgt[e]], 1);
}

// Per-block scan: exclusive per-element offsets (block-local) + block totals.
__global__ __launch_bounds__(SCAN_B) void scan1_kernel(const int* __restrict__ cnt,
                                                       int* __restrict__ off,
                                                       int* __restrict__ bsum, int N) {
    __shared__ int lds[SCAN_B];
    int tid = threadIdx.x;
    int base = blockIdx.x * SCAN_E + tid * 4;
    int4 c = make_int4(0, 0, 0, 0);
    if (base + 3 < N) {
        c = *(const int4*)(cnt + base);
    } else if (base < N) {
        c.x = cnt[base];
        if (base + 1 < N) c.y = cnt[base + 1];
        if (base + 2 < N) c.z = cnt[base + 2];
    }
    int s0 = c.x, s1 = s0 + c.y, s2 = s1 + c.z, s3 = s2 + c.w;
    lds[tid] = s3;
    __syncthreads();
    for (int d = 1; d < SCAN_B; d <<= 1) {
        int v = (tid >= d) ? lds[tid - d] : 0;
        __syncthreads();
        lds[tid] += v;
        __syncthreads();
    }
    int excl = tid ? lds[tid - 1] : 0;
    int4 o = make_int4(excl, excl + s0, excl + s1, excl + s2);
    if (base + 3 < N) {
        *(int4*)(off + base) = o;
    } else if (base < N) {
        off[base] = o.x;
        if (base + 1 < N) off[base + 1] = o.y;
        if (base + 2 < N) off[base + 2] = o.z;
    }
    if (tid == SCAN_B - 1) bsum[blockIdx.x] = lds[tid];
}

// Fixup: each block computes the exclusive prefix of bsum (wave-reduced in
// registers, <=64 entries per 64-lane chunk), adds it, writes off and run.
__global__ __launch_bounds__(SCAN_B) void scan2_kernel(int* __restrict__ off,
                                                       int* __restrict__ run,
                                                       const int* __restrict__ bsum,
                                                       int N, int E) {
    __shared__ int s_pre;
    int tid = threadIdx.x;
    int b = blockIdx.x;
    if (tid < 64) {
        int pre = 0;
        for (int basej = 0; basej < b; basej += 64) {
            int v = (basej + tid < b) ? bsum[basej + tid] : 0;
            for (int d2 = 1; d2 < 64; d2 <<= 1) v += __shfl_xor(v, d2);
            pre += v;
        }
        if (tid == 0) s_pre = pre;
    }
    __syncthreads();
    int pre = s_pre;
    int base = b * SCAN_E + tid * 4;
    if (base + 3 < N) {
        int4 o = *(int4*)(off + base);
        o.x += pre; o.y += pre; o.z += pre; o.w += pre;
        *(int4*)(off + base) = o;
        *(int4*)(run + base) = o;
    } else if (base < N) {
        for (int k = 0; k < 4 && base + k < N; ++k) {
            int v = off[base + k] + pre;
            off[base + k] = v;
            run[base + k] = v;
        }
    }
    if (b == 0 && tid == 0) off[N] = E;
}

__global__ void scatter_kernel(const int* __restrict__ tgt, const int* __restrict__ src,
                               int* __restrict__ run, int* __restrict__ ssrc, int E) {
    int e = blockIdx.x * blockDim.x + threadIdx.x;
    if (e < E) {
        int pos = atomicAdd(&run[tgt[e]], 1);
        ssrc[pos] = src[e];
    }
}

// One wave per node. 16 lanes x float4 per row => 4 source rows in flight.
// Inner trip count is wave-uniform; __shfl always executes with all 64 lanes
// active (source lane clamped), only the load/accumulate is predicated.
__global__ __launch_bounds__(256) void segsum_kernel(const int* __restrict__ off,
                                                     const int* __restrict__ ssrc,
                                                     const float4* __restrict__ x4,
                                                     float4* __restrict__ out4, int N) {
    int wave = (int)((blockIdx.x * 256u + threadIdx.x) >> 6);
    int lane = threadIdx.x & 63;
    int grp = lane >> 4;   // which of 4 rows in flight
    int l16 = lane & 15;   // float4 index within the row (16 x float4 = 64 f32)
    if (wave >= N) return;
    int start = off[wave];
    int end = off[wave + 1];
    float4 acc = make_float4(0.f, 0.f, 0.f, 0.f);
    for (int i = start; i < end; i += 64) {
        int n = end - i; if (n > 64) n = 64;
        int idx = (i + lane < end) ? ssrc[i + lane] : 0;
        int trips = (n + 3) >> 2;              // wave-uniform
        for (int k = 0; k < trips; ++k) {
            int j = grp + (k << 2);
            int s = __shfl(idx, j < n ? j : 0);  // all lanes active at the shfl
            if (j < n) {
                float4 v = x4[(long long)s * 16 + l16];
                acc.x += v.x; acc.y += v.y; acc.z += v.z; acc.w += v.w;
            }
        }
    }
    // combine the 4 per-group partials (butterfly across lane bits 16, 32)
    for (int d2 = 16; d2 < 64; d2 <<= 1) {
        acc.x += __shfl_xor(acc.x, d2);
        acc.y += __shfl_xor(acc.y, d2);
        acc.z += __shfl_xor(acc.z, d2);
        acc.w += __shfl_xor(acc.w, d2);
    }
    if (grp == 0) out4[(long long)wave * 16 + l16] = acc;
}

// Fallback (ws too small): direct atomic scatter-add.
__global__ void mp_scatter_add_kernel(const int* __restrict__ tgt,
                                      const int* __restrict__ src,
                                      const float* __restrict__ x,
                                      float* __restrict__ out,
                                      int E) {
    long long tid = (long long)blockIdx.x * blockDim.x + threadIdx.x;
    int e = (int)(tid >> 6);
    int d = (int)(tid & 63);
    if (e >= E) return;
    atomicAdd(&out[(long long)tgt[e] * D + d], x[(long long)src[e] * D + d]);
}

extern "C" void kernel_launch(void* const* d_in, const int* in_sizes, int n_in,
                              void* d_out, int out_size, void* d_ws, size_t ws_size,
                              hipStream_t stream) {
    const int* edge_index = (const int*)d_in[0];   // [2, E]
    const float* x        = (const float*)d_in[1]; // [N, 64]
    float* out            = (float*)d_out;         // [N, 64]

    int E = in_sizes[0] / 2;
    int N = out_size / D;
    const int* tgt = edge_index;       // edge_index[0]
    const int* src = edge_index + E;   // edge_index[1]

    int NB = (N + SCAN_E - 1) / SCAN_E;

    // ws layout (ints, each segment 16B-aligned): off[N+1] | run[N] | cnt[N] | bsum[NB] | ssrc[E]
    size_t offSz  = ((size_t)(N + 1) + 3) & ~(size_t)3;
    size_t runSz  = ((size_t)N + 3) & ~(size_t)3;
    size_t cntSz  = runSz;
    size_t bsumSz = ((size_t)NB + 3) & ~(size_t)3;
    size_t need = (offSz + runSz + cntSz + bsumSz + (size_t)E) * sizeof(int);

    if (ws_size < need) {
        hipMemsetAsync(d_out, 0, (size_t)out_size * sizeof(float), stream);
        long long total = (long long)E * D;
        int block = 256;
        long long grid = (total + block - 1) / block;
        mp_scatter_add_kernel<<<(dim3)(unsigned)grid, block, 0, stream>>>(tgt, src, x, out, E);
        return;
    }

    int* off  = (int*)d_ws;
    int* run  = off + offSz;
    int* cnt  = run + runSz;
    int* bsum = cnt + cntSz;
    int* ssrc = bsum + bsumSz;

    hipMemsetAsync(cnt, 0, (size_t)N * sizeof(int), stream);

    int block = 256;
    int gridE = (E + block - 1) / block;
    hist_kernel<<<gridE, block, 0, stream>>>(tgt, cnt, E);
    scan1_kernel<<<NB, SCAN_B, 0, stream>>>(cnt, off, bsum, N);
    scan2_kernel<<<NB, SCAN_B, 0, stream>>>(off, run, bsum, N, E);
    scatter_kernel<<<gridE, block, 0, stream>>>(tgt, src, run, ssrc, E);

    long long totalW = (long long)N * 64;
    long long gridN = (totalW + block - 1) / block;
    segsum_kernel<<<(dim3)(unsigned)gridN, block, 0, stream>>>(off, ssrc, (const float4*)x,
                                                              (float4*)out, N);
}